// Round 1
// baseline (115.874 us; speedup 1.0000x reference)
//
#include <hip/hip_runtime.h>

#define NQ 11
#define NL 4
#define NF 8
#define DIM 2048   // 2^11

// Composed permutation of the CNOT ring (0,1)(1,2)...(9,10)(10,0).
// Each CNOT(c,t) maps basis index bits bit_t ^= bit_c (bit of qubit q at
// position 10-q). Sequential state updates compose so that
// s_final[y] = s_0[M_1(M_2(...(M_11(y))))], M_11 applied first.
__device__ __forceinline__ int ring_perm(int y) {
    int z = y ^ ((y & 1) << 10);           // M11: CNOT(10,0): bit_0(pos10) ^= bit_10(pos0)
#pragma unroll
    for (int k = 10; k >= 1; --k) {        // M_k: CNOT(k-1,k): bit_k(pos 10-k) ^= bit_{k-1}(pos 11-k)
        z ^= ((z >> (11 - k)) & 1) << (10 - k);
    }
    return z;
}

__global__ __launch_bounds__(1024)
void qsim_kernel(const float* __restrict__ X, const float* __restrict__ W,
                 const float* __restrict__ Bi, float* __restrict__ out)
{
    __shared__ float2 bufA[DIM];
    __shared__ float2 bufB[DIM];
    __shared__ float red[16][4];

    const int b = blockIdx.x;
    const int t = threadIdx.x;

    float2* cur = bufA;
    float2* nxt = bufB;

    // init |0...0>
    cur[t]        = make_float2(0.f, 0.f);
    cur[t + 1024] = make_float2(0.f, 0.f);
    if (t == 0) cur[0] = make_float2(1.f, 0.f);

    // per-sample features (broadcast load, L1-served)
    float xr[NF];
#pragma unroll
    for (int f = 0; f < NF; ++f) xr[f] = X[b * NF + f];

    __syncthreads();

    for (int l = 0; l < NL; ++l) {
        for (int q = 0; q < NQ; ++q) {
            const int base = (l * NQ + q) * 3;
            // Xe[b, j] = X[b, j % 8], j = base + c
            const float phi   = xr[(base + 0) & 7] * W[base + 0] + Bi[base + 0];
            const float theta = xr[(base + 1) & 7] * W[base + 1] + Bi[base + 1];
            const float omega = xr[(base + 2) & 7] * W[base + 2] + Bi[base + 2];

            float sh, ch;   sincosf(0.5f * theta, &sh, &ch);
            float spo, cpo; sincosf(0.5f * (phi + omega), &spo, &cpo);
            float spm, cpm; sincosf(0.5f * (phi - omega), &spm, &cpm);
            // m00 = e^{-i po} ct ; m01 = -e^{+i pm} st
            // m10 = e^{-i pm} st ; m11 = e^{+i po} ct
            const float m00r =  cpo * ch, m00i = -spo * ch;
            const float m01r = -cpm * sh, m01i = -spm * sh;
            const float m10r =  cpm * sh, m10i = -spm * sh;
            const float m11r =  cpo * ch, m11i =  spo * ch;

            const int p  = 10 - q;        // bit position of qubit q
            const int m  = 1 << p;
            const int i0 = ((t >> p) << (p + 1)) | (t & (m - 1));
            const int i1 = i0 | m;

            const float2 a = cur[i0];
            const float2 c = cur[i1];
            float2 na, nc;
            na.x = m00r * a.x - m00i * a.y + m01r * c.x - m01i * c.y;
            na.y = m00r * a.y + m00i * a.x + m01r * c.y + m01i * c.x;
            nc.x = m10r * a.x - m10i * a.y + m11r * c.x - m11i * c.y;
            nc.y = m10r * a.y + m10i * a.x + m11r * c.y + m11i * c.x;
            cur[i0] = na;
            cur[i1] = nc;
            __syncthreads();
        }
        // all 11 ring CNOTs as ONE basis permutation (gather into ping-pong buf)
        nxt[t]        = cur[ring_perm(t)];
        nxt[t + 1024] = cur[ring_perm(t + 1024)];
        __syncthreads();
        float2* tmp = cur; cur = nxt; nxt = tmp;
    }

    // Z-expectation on qubits 0..3 (bit positions 10..7)
    float v[4];
    {
        const int iA = t, iB = t + 1024;
        const float2 a = cur[iA];
        const float2 c = cur[iB];
        const float pa = a.x * a.x + a.y * a.y;
        const float pc = c.x * c.x + c.y * c.y;
#pragma unroll
        for (int k = 0; k < 4; ++k) {
            const int pos = 10 - k;
            const float sa = 1.f - 2.f * (float)((iA >> pos) & 1);
            const float sc = 1.f - 2.f * (float)((iB >> pos) & 1);
            v[k] = sa * pa + sc * pc;
        }
    }
#pragma unroll
    for (int k = 0; k < 4; ++k) {
#pragma unroll
        for (int off = 32; off >= 1; off >>= 1)
            v[k] += __shfl_down(v[k], off, 64);
    }
    const int lane = t & 63;
    const int wave = t >> 6;
    if (lane == 0) {
#pragma unroll
        for (int k = 0; k < 4; ++k) red[wave][k] = v[k];
    }
    __syncthreads();
    if (t < 4) {
        float s = 0.f;
#pragma unroll
        for (int w = 0; w < 16; ++w) s += red[w][t];
        out[b * 4 + t] = s;
    }
}

extern "C" void kernel_launch(void* const* d_in, const int* in_sizes, int n_in,
                              void* d_out, int out_size, void* d_ws, size_t ws_size,
                              hipStream_t stream) {
    const float* X  = (const float*)d_in[0];   // (16, 8)
    const float* W  = (const float*)d_in[1];   // (4, 11, 3)
    const float* Bi = (const float*)d_in[2];   // (4, 11, 3)
    float* out = (float*)d_out;                // (16, 4)
    qsim_kernel<<<16, 1024, 0, stream>>>(X, W, Bi, out);
}

// Round 2
// 72.047 us; speedup vs baseline: 1.6083x; 1.6083x over previous
//
#include <hip/hip_runtime.h>

#define NQ 11
#define NL 4
#define NF 8
#define DIM 2048   // 2^11
#define NGATES (NL * NQ)  // 44

// Composed permutation of the CNOT ring (0,1)(1,2)...(9,10)(10,0).
// s_final[y] = s_0[M_1(M_2(...(M_11(y))))], M_11 applied first.
__device__ __forceinline__ int ring_perm(int y) {
    int z = y ^ ((y & 1) << 10);           // M11: CNOT(10,0)
#pragma unroll
    for (int k = 10; k >= 1; --k) {        // M_k: CNOT(k-1,k)
        z ^= ((z >> (11 - k)) & 1) << (10 - k);
    }
    return z;
}

__global__ __launch_bounds__(1024)
void qsim_kernel(const float* __restrict__ X, const float* __restrict__ W,
                 const float* __restrict__ Bi, float* __restrict__ out)
{
    __shared__ float2 bufA[DIM];
    __shared__ float2 bufB[DIM];
    __shared__ float gm[NGATES][8];   // per-gate 2x2 complex matrix
    __shared__ float red[16][4];

    const int b = blockIdx.x;
    const int t = threadIdx.x;

    float2* cur = bufA;
    float2* nxt = bufB;

    // init |0...0>
    cur[t]        = make_float2(0.f, 0.f);
    cur[t + 1024] = make_float2(0.f, 0.f);
    if (t == 0) cur[0] = make_float2(1.f, 0.f);

    // --- precompute all 44 gate matrices (one thread per gate) ---
    if (t < NGATES) {
        const int base = t * 3;
        const float x0 = X[b * NF + ((base + 0) & 7)];
        const float x1 = X[b * NF + ((base + 1) & 7)];
        const float x2 = X[b * NF + ((base + 2) & 7)];
        const float phi   = x0 * W[base + 0] + Bi[base + 0];
        const float theta = x1 * W[base + 1] + Bi[base + 1];
        const float omega = x2 * W[base + 2] + Bi[base + 2];

        float sh, ch;   sincosf(0.5f * theta, &sh, &ch);
        float spo, cpo; sincosf(0.5f * (phi + omega), &spo, &cpo);
        float spm, cpm; sincosf(0.5f * (phi - omega), &spm, &cpm);
        gm[t][0] =  cpo * ch;  gm[t][1] = -spo * ch;   // m00
        gm[t][2] = -cpm * sh;  gm[t][3] = -spm * sh;   // m01
        gm[t][4] =  cpm * sh;  gm[t][5] = -spm * sh;   // m10
        gm[t][6] =  cpo * ch;  gm[t][7] =  spo * ch;   // m11
    }
    __syncthreads();

    for (int l = 0; l < NL; ++l) {
#pragma unroll
        for (int q = 0; q < NQ; ++q) {
            const int g = l * NQ + q;
            // uniform-address LDS broadcast of the 2x2 matrix
            const float4* gmv = (const float4*)gm[g];
            const float4 M0 = gmv[0];   // m00r m00i m01r m01i
            const float4 M1 = gmv[1];   // m10r m10i m11r m11i

            const int p  = 10 - q;
            const int m  = 1 << p;
            const int i0 = ((t >> p) << (p + 1)) | (t & (m - 1));
            const int i1 = i0 | m;

            const float2 a = cur[i0];
            const float2 c = cur[i1];
            float2 na, nc;
            na.x = M0.x * a.x - M0.y * a.y + M0.z * c.x - M0.w * c.y;
            na.y = M0.x * a.y + M0.y * a.x + M0.z * c.y + M0.w * c.x;
            nc.x = M1.x * a.x - M1.y * a.y + M1.z * c.x - M1.w * c.y;
            nc.y = M1.x * a.y + M1.y * a.x + M1.z * c.y + M1.w * c.x;
            cur[i0] = na;
            cur[i1] = nc;
            __syncthreads();
        }
        // all 11 ring CNOTs as ONE basis permutation (gather into ping-pong buf)
        nxt[t]        = cur[ring_perm(t)];
        nxt[t + 1024] = cur[ring_perm(t + 1024)];
        __syncthreads();
        float2* tmp = cur; cur = nxt; nxt = tmp;
    }

    // Z-expectation on qubits 0..3 (bit positions 10..7)
    float v[4];
    {
        const int iA = t, iB = t + 1024;
        const float2 a = cur[iA];
        const float2 c = cur[iB];
        const float pa = a.x * a.x + a.y * a.y;
        const float pc = c.x * c.x + c.y * c.y;
#pragma unroll
        for (int k = 0; k < 4; ++k) {
            const int pos = 10 - k;
            const float sa = 1.f - 2.f * (float)((iA >> pos) & 1);
            const float sc = 1.f - 2.f * (float)((iB >> pos) & 1);
            v[k] = sa * pa + sc * pc;
        }
    }
#pragma unroll
    for (int k = 0; k < 4; ++k) {
#pragma unroll
        for (int off = 32; off >= 1; off >>= 1)
            v[k] += __shfl_down(v[k], off, 64);
    }
    const int lane = t & 63;
    const int wave = t >> 6;
    if (lane == 0) {
#pragma unroll
        for (int k = 0; k < 4; ++k) red[wave][k] = v[k];
    }
    __syncthreads();
    if (t < 4) {
        float s = 0.f;
#pragma unroll
        for (int w = 0; w < 16; ++w) s += red[w][t];
        out[b * 4 + t] = s;
    }
}

extern "C" void kernel_launch(void* const* d_in, const int* in_sizes, int n_in,
                              void* d_out, int out_size, void* d_ws, size_t ws_size,
                              hipStream_t stream) {
    const float* X  = (const float*)d_in[0];   // (16, 8)
    const float* W  = (const float*)d_in[1];   // (4, 11, 3)
    const float* Bi = (const float*)d_in[2];   // (4, 11, 3)
    float* out = (float*)d_out;                // (16, 4)
    qsim_kernel<<<16, 1024, 0, stream>>>(X, W, Bi, out);
}

// Round 3
// 69.126 us; speedup vs baseline: 1.6763x; 1.0423x over previous
//
#include <hip/hip_runtime.h>

#define NQ 11
#define NL 4
#define NF 8
#define DIM 2048   // 2^11
#define NGATES (NL * NQ)  // 44

// Composed permutation of the CNOT ring (0,1)(1,2)...(9,10)(10,0).
// s_after_cnots[i] = s_before[ring_perm(i)]  (verified absmax==0 in R1/R2).
// Linear over GF(2): ring_perm(a^b) = ring_perm(a)^ring_perm(b).
__host__ __device__ constexpr int ring_perm(int y) {
    int z = y ^ ((y & 1) << 10);
    for (int k = 10; k >= 1; --k)
        z ^= ((z >> (11 - k)) & 1) << (10 - k);
    return z;
}

// XOR bank swizzle: bijective, spreads power-of-2 strides across banks.
__device__ __forceinline__ int swz(int i) { return i ^ ((i >> 5) & 31); }

// pair update: a' = m00 a + m01 c ; c' = m10 a + m11 c
// M0 = (m00r,m00i,m01r,m01i), M1 = (m10r,m10i,m11r,m11i)
__device__ __forceinline__ void rot_pair(float2& a, float2& c,
                                         const float4 M0, const float4 M1) {
    float2 na, nc;
    na.x = M0.x * a.x - M0.y * a.y + M0.z * c.x - M0.w * c.y;
    na.y = M0.x * a.y + M0.y * a.x + M0.z * c.y + M0.w * c.x;
    nc.x = M1.x * a.x - M1.y * a.y + M1.z * c.x - M1.w * c.y;
    nc.y = M1.x * a.y + M1.y * a.x + M1.z * c.y + M1.w * c.x;
    a = na; c = nc;
}

// One LDS pass applying 3 single-qubit gates at bit positions P2>P1>P0.
// g = gate index of the qubit at P2 (qubits at P2,P1,P0 are g,g+1,g+2).
// If PERM, reads are routed through ring_perm (folds the previous layer's
// CNOT ring into this pass's gather). Writes always go to logical addresses.
template<int P2, int P1, int P0, bool PERM>
__device__ __forceinline__ void group3(const float2* __restrict__ src,
                                       float2* __restrict__ dst,
                                       const float (*gm)[8], int g, int base) {
    constexpr int E2 = 1 << P2, E1 = 1 << P1, E0 = 1 << P0;
    constexpr int K2 = PERM ? ring_perm(1 << P2) : (1 << P2);
    constexpr int K1 = PERM ? ring_perm(1 << P1) : (1 << P1);
    constexpr int K0 = PERM ? ring_perm(1 << P0) : (1 << P0);

    const float4* mA = (const float4*)gm[g];       // qubit at P2
    const float4* mB = (const float4*)gm[g + 1];   // qubit at P1
    const float4* mC = (const float4*)gm[g + 2];   // qubit at P0
    const float4 A0 = mA[0], A1 = mA[1];
    const float4 B0 = mB[0], B1 = mB[1];
    const float4 C0 = mC[0], C1 = mC[1];

    const int rb = PERM ? ring_perm(base) : base;
    float2 s[8];
#pragma unroll
    for (int k = 0; k < 8; ++k) {
        const int idx = rb ^ ((k & 4) ? K2 : 0) ^ ((k & 2) ? K1 : 0) ^ ((k & 1) ? K0 : 0);
        s[k] = src[swz(idx)];
    }
    // gate at P2 (lowest qubit number first — same order as reference)
    rot_pair(s[0], s[4], A0, A1); rot_pair(s[1], s[5], A0, A1);
    rot_pair(s[2], s[6], A0, A1); rot_pair(s[3], s[7], A0, A1);
    // gate at P1
    rot_pair(s[0], s[2], B0, B1); rot_pair(s[1], s[3], B0, B1);
    rot_pair(s[4], s[6], B0, B1); rot_pair(s[5], s[7], B0, B1);
    // gate at P0
    rot_pair(s[0], s[1], C0, C1); rot_pair(s[2], s[3], C0, C1);
    rot_pair(s[4], s[5], C0, C1); rot_pair(s[6], s[7], C0, C1);
#pragma unroll
    for (int k = 0; k < 8; ++k) {
        const int a = base | ((k & 4) ? E2 : 0) | ((k & 2) ? E1 : 0) | ((k & 1) ? E0 : 0);
        dst[swz(a)] = s[k];
    }
}

// 2-qubit group at bit positions (1,0): qubits g (pos1) and g+1 (pos0).
// Each thread handles two independent quads (256 threads * 8 amps = 2048).
__device__ __forceinline__ void group2q(float2* buf, const float (*gm)[8],
                                        int g, int t) {
    const float4* mB = (const float4*)gm[g];
    const float4* mC = (const float4*)gm[g + 1];
    const float4 B0 = mB[0], B1 = mB[1];
    const float4 C0 = mC[0], C1 = mC[1];
#pragma unroll
    for (int j = 0; j < 2; ++j) {
        const int base = (t + 256 * j) << 2;
        float2 s[4];
#pragma unroll
        for (int k = 0; k < 4; ++k) s[k] = buf[swz(base | k)];
        rot_pair(s[0], s[2], B0, B1); rot_pair(s[1], s[3], B0, B1);   // pos1
        rot_pair(s[0], s[1], C0, C1); rot_pair(s[2], s[3], C0, C1);   // pos0
#pragma unroll
        for (int k = 0; k < 4; ++k) buf[swz(base | k)] = s[k];
    }
}

__global__ __launch_bounds__(256)
void qsim_kernel(const float* __restrict__ X, const float* __restrict__ W,
                 const float* __restrict__ Bi, float* __restrict__ out)
{
    __shared__ float2 bufA[DIM];
    __shared__ float2 bufB[DIM];
    __shared__ __align__(16) float gm[NGATES][8];
    __shared__ float red[4][4];

    const int b = blockIdx.x;
    const int t = threadIdx.x;

    // --- all 44 gate matrices (one thread per gate) ---
    if (t < NGATES) {
        const int base = t * 3;
        const float x0 = X[b * NF + ((base + 0) & 7)];
        const float x1 = X[b * NF + ((base + 1) & 7)];
        const float x2 = X[b * NF + ((base + 2) & 7)];
        const float phi   = x0 * W[base + 0] + Bi[base + 0];
        const float theta = x1 * W[base + 1] + Bi[base + 1];
        const float omega = x2 * W[base + 2] + Bi[base + 2];
        float sh, ch;   sincosf(0.5f * theta, &sh, &ch);
        float spo, cpo; sincosf(0.5f * (phi + omega), &spo, &cpo);
        float spm, cpm; sincosf(0.5f * (phi - omega), &spm, &cpm);
        gm[t][0] =  cpo * ch;  gm[t][1] = -spo * ch;   // m00
        gm[t][2] = -cpm * sh;  gm[t][3] = -spm * sh;   // m01
        gm[t][4] =  cpm * sh;  gm[t][5] = -spm * sh;   // m10
        gm[t][6] =  cpo * ch;  gm[t][7] =  spo * ch;   // m11
    }
    // --- init |0...0> ---
#pragma unroll
    for (int k = 0; k < 8; ++k) bufA[swz(t + 256 * k)] = make_float2(0.f, 0.f);
    if (t == 0) bufA[0] = make_float2(1.f, 0.f);   // swz(0)==0
    __syncthreads();

    float2* S = bufA;
    float2* T = bufB;
    const int base765 = ((t >> 5) << 8) | (t & 31);  // free bits {0..4,8..10}
    const int base432 = ((t >> 2) << 5) | (t & 3);   // free bits {0,1,5..10}

    // layer 0 (no preceding CNOTs)
    group3<10, 9, 8, false>(S, T, gm, 0, t); { float2* x = S; S = T; T = x; }
    __syncthreads();
    group3<7, 6, 5, false>(S, S, gm, 3, base765);  __syncthreads();
    group3<4, 3, 2, false>(S, S, gm, 6, base432);  __syncthreads();
    group2q(S, gm, 9, t);                          __syncthreads();

    // layers 1..3: previous layer's CNOT ring folded into group0's gather
    for (int l = 1; l < NL; ++l) {
        group3<10, 9, 8, true>(S, T, gm, l * NQ + 0, t); { float2* x = S; S = T; T = x; }
        __syncthreads();
        group3<7, 6, 5, false>(S, S, gm, l * NQ + 3, base765);  __syncthreads();
        group3<4, 3, 2, false>(S, S, gm, l * NQ + 6, base432);  __syncthreads();
        group2q(S, gm, l * NQ + 9, t);                          __syncthreads();
    }

    // measurement: fold the final CNOT ring into the probability gather.
    // logical index i = t + 256k; source = ring_perm(i) by linearity.
    const int rp_t = ring_perm(t);
    float v[4] = {0.f, 0.f, 0.f, 0.f};
#pragma unroll
    for (int k = 0; k < 8; ++k) {
        const int src = rp_t ^ ((k & 4) ? ring_perm(1 << 10) : 0)
                             ^ ((k & 2) ? ring_perm(1 << 9)  : 0)
                             ^ ((k & 1) ? ring_perm(1 << 8)  : 0);
        const float2 a = S[swz(src)];
        const float p = a.x * a.x + a.y * a.y;
        v[0] += (k & 4) ? -p : p;          // qubit 0, bit pos 10
        v[1] += (k & 2) ? -p : p;          // qubit 1, bit pos 9
        v[2] += (k & 1) ? -p : p;          // qubit 2, bit pos 8
        v[3] += (t & 128) ? -p : p;        // qubit 3, bit pos 7
    }
#pragma unroll
    for (int q = 0; q < 4; ++q)
#pragma unroll
        for (int off = 32; off >= 1; off >>= 1)
            v[q] += __shfl_down(v[q], off, 64);
    if ((t & 63) == 0) {
#pragma unroll
        for (int q = 0; q < 4; ++q) red[t >> 6][q] = v[q];
    }
    __syncthreads();
    if (t < 4) {
        out[b * 4 + t] = red[0][t] + red[1][t] + red[2][t] + red[3][t];
    }
}

extern "C" void kernel_launch(void* const* d_in, const int* in_sizes, int n_in,
                              void* d_out, int out_size, void* d_ws, size_t ws_size,
                              hipStream_t stream) {
    const float* X  = (const float*)d_in[0];   // (16, 8)
    const float* W  = (const float*)d_in[1];   // (4, 11, 3)
    const float* Bi = (const float*)d_in[2];   // (4, 11, 3)
    float* out = (float*)d_out;                // (16, 4)
    qsim_kernel<<<16, 256, 0, stream>>>(X, W, Bi, out);
}

// Round 4
// 67.107 us; speedup vs baseline: 1.7267x; 1.0301x over previous
//
#include <hip/hip_runtime.h>

#define NQ 11
#define NL 4
#define NF 8
#define DIM 2048   // 2^11
#define NGATES (NL * NQ)  // 44

// Composed permutation of the CNOT ring (0,1)(1,2)...(9,10)(10,0).
// s_after_cnots[i] = s_before[ring_perm(i)]  (verified absmax==0 in R1/R2/R3).
// Linear over GF(2): ring_perm(a^b) = ring_perm(a)^ring_perm(b).
__host__ __device__ constexpr int ring_perm(int y) {
    int z = y ^ ((y & 1) << 10);
    for (int k = 10; k >= 1; --k)
        z ^= ((z >> (11 - k)) & 1) << (10 - k);
    return z;
}

// XOR bank swizzle: bijective, spreads power-of-2 strides across banks.
__device__ __forceinline__ int swz(int i) { return i ^ ((i >> 5) & 31); }

__device__ __forceinline__ float2 cmul(float2 a, float2 b) {
    return make_float2(a.x * b.x - a.y * b.y, a.x * b.y + a.y * b.x);
}

// pair update: a' = m00 a + m01 c ; c' = m10 a + m11 c
__device__ __forceinline__ void rot_pair(float2& a, float2& c,
                                         const float4 M0, const float4 M1) {
    float2 na, nc;
    na.x = M0.x * a.x - M0.y * a.y + M0.z * c.x - M0.w * c.y;
    na.y = M0.x * a.y + M0.y * a.x + M0.z * c.y + M0.w * c.x;
    nc.x = M1.x * a.x - M1.y * a.y + M1.z * c.x - M1.w * c.y;
    nc.y = M1.x * a.y + M1.y * a.x + M1.z * c.y + M1.w * c.x;
    a = na; c = nc;
}

// One LDS pass applying 3 single-qubit gates at bit positions P2>P1>P0.
// If PERM, reads are routed through ring_perm (folds the previous layer's
// CNOT ring into this pass's gather). Writes always go to logical addresses.
template<int P2, int P1, int P0, bool PERM>
__device__ __forceinline__ void group3(const float2* __restrict__ src,
                                       float2* __restrict__ dst,
                                       const float (*gm)[8], int g, int base) {
    constexpr int E2 = 1 << P2, E1 = 1 << P1, E0 = 1 << P0;
    constexpr int K2 = PERM ? ring_perm(1 << P2) : (1 << P2);
    constexpr int K1 = PERM ? ring_perm(1 << P1) : (1 << P1);
    constexpr int K0 = PERM ? ring_perm(1 << P0) : (1 << P0);

    const float4* mA = (const float4*)gm[g];
    const float4* mB = (const float4*)gm[g + 1];
    const float4* mC = (const float4*)gm[g + 2];
    const float4 A0 = mA[0], A1 = mA[1];
    const float4 B0 = mB[0], B1 = mB[1];
    const float4 C0 = mC[0], C1 = mC[1];

    const int rb = PERM ? ring_perm(base) : base;
    float2 s[8];
#pragma unroll
    for (int k = 0; k < 8; ++k) {
        const int idx = rb ^ ((k & 4) ? K2 : 0) ^ ((k & 2) ? K1 : 0) ^ ((k & 1) ? K0 : 0);
        s[k] = src[swz(idx)];
    }
    rot_pair(s[0], s[4], A0, A1); rot_pair(s[1], s[5], A0, A1);
    rot_pair(s[2], s[6], A0, A1); rot_pair(s[3], s[7], A0, A1);
    rot_pair(s[0], s[2], B0, B1); rot_pair(s[1], s[3], B0, B1);
    rot_pair(s[4], s[6], B0, B1); rot_pair(s[5], s[7], B0, B1);
    rot_pair(s[0], s[1], C0, C1); rot_pair(s[2], s[3], C0, C1);
    rot_pair(s[4], s[5], C0, C1); rot_pair(s[6], s[7], C0, C1);
#pragma unroll
    for (int k = 0; k < 8; ++k) {
        const int a = base | ((k & 4) ? E2 : 0) | ((k & 2) ? E1 : 0) | ((k & 1) ? E0 : 0);
        dst[swz(a)] = s[k];
    }
}

// 2-qubit group at bit positions (1,0): qubits g (pos1) and g+1 (pos0).
__device__ __forceinline__ void group2q(float2* buf, const float (*gm)[8],
                                        int g, int t) {
    const float4* mB = (const float4*)gm[g];
    const float4* mC = (const float4*)gm[g + 1];
    const float4 B0 = mB[0], B1 = mB[1];
    const float4 C0 = mC[0], C1 = mC[1];
#pragma unroll
    for (int j = 0; j < 2; ++j) {
        const int base = (t + 256 * j) << 2;
        float2 s[4];
#pragma unroll
        for (int k = 0; k < 4; ++k) s[k] = buf[swz(base | k)];
        rot_pair(s[0], s[2], B0, B1); rot_pair(s[1], s[3], B0, B1);
        rot_pair(s[0], s[1], C0, C1); rot_pair(s[2], s[3], C0, C1);
#pragma unroll
        for (int k = 0; k < 4; ++k) buf[swz(base | k)] = s[k];
    }
}

__global__ __launch_bounds__(256)
void qsim_kernel(const float* __restrict__ X, const float* __restrict__ W,
                 const float* __restrict__ Bi, float* __restrict__ out)
{
    __shared__ float2 bufA[DIM];
    __shared__ float2 bufB[DIM];
    __shared__ __align__(16) float gm[NGATES][8];
    __shared__ float red[4][4];

    const int b = blockIdx.x;
    const int t = threadIdx.x;

    // --- all 44 gate matrices (one thread per gate) ---
    if (t < NGATES) {
        const int base = t * 3;
        const float x0 = X[b * NF + ((base + 0) & 7)];
        const float x1 = X[b * NF + ((base + 1) & 7)];
        const float x2 = X[b * NF + ((base + 2) & 7)];
        const float phi   = x0 * W[base + 0] + Bi[base + 0];
        const float theta = x1 * W[base + 1] + Bi[base + 1];
        const float omega = x2 * W[base + 2] + Bi[base + 2];
        float sh, ch;   sincosf(0.5f * theta, &sh, &ch);
        float spo, cpo; sincosf(0.5f * (phi + omega), &spo, &cpo);
        float spm, cpm; sincosf(0.5f * (phi - omega), &spm, &cpm);
        gm[t][0] =  cpo * ch;  gm[t][1] = -spo * ch;   // m00
        gm[t][2] = -cpm * sh;  gm[t][3] = -spm * sh;   // m01
        gm[t][4] =  cpm * sh;  gm[t][5] = -spm * sh;   // m10
        gm[t][6] =  cpo * ch;  gm[t][7] =  spo * ch;   // m11
    }
    __syncthreads();

    float2* S = bufA;
    float2* T = bufB;

    // --- layer 0 in closed form: Rot gates on |0..0> give a product state,
    //     amp[x] = prod_q Mq[bit_{10-q}(x)][0]. Gates commute (disjoint
    //     qubits), so the product is exact up to fp reassociation.
    {
        // column-0 entries (m00, m10) for gates 0..10; gate q acts on bit 10-q,
        // i.e. bit b belongs to gate 10-b.
        float2 c0[11], c1[11];
#pragma unroll
        for (int q = 0; q < 11; ++q) {
            c0[q] = make_float2(gm[q][0], gm[q][1]);   // m00
            c1[q] = make_float2(gm[q][4], gm[q][5]);   // m10
        }
        // base product over bits 0..7 (from t)
        float2 P = ((t >> 0) & 1) ? c1[10] : c0[10];
#pragma unroll
        for (int bbit = 1; bbit < 8; ++bbit)
            P = cmul(P, ((t >> bbit) & 1) ? c1[10 - bbit] : c0[10 - bbit]);
        // combos over bits 8,9,10 (gates 2,1,0)
        float2 t2[4];
        t2[0] = cmul(c0[1], c0[0]);   // bit9=0, bit10=0
        t2[1] = cmul(c1[1], c0[0]);   // bit9=1, bit10=0
        t2[2] = cmul(c0[1], c1[0]);   // bit9=0, bit10=1
        t2[3] = cmul(c1[1], c1[0]);   // bit9=1, bit10=1
#pragma unroll
        for (int k = 0; k < 8; ++k) {
            const float2 h = cmul((k & 1) ? c1[2] : c0[2], t2[k >> 1]);
            S[swz(t + 256 * k)] = cmul(P, h);
        }
    }
    __syncthreads();

    // layers 1..3: previous layer's CNOT ring folded into group0's gather
    for (int l = 1; l < NL; ++l) {
        group3<10, 9, 8, true>(S, T, gm, l * NQ + 0, t); { float2* x = S; S = T; T = x; }
        __syncthreads();
        const int base765 = ((t >> 5) << 8) | (t & 31);
        const int base432 = ((t >> 2) << 5) | (t & 3);
        group3<7, 6, 5, false>(S, S, gm, l * NQ + 3, base765);  __syncthreads();
        group3<4, 3, 2, false>(S, S, gm, l * NQ + 6, base432);  __syncthreads();
        group2q(S, gm, l * NQ + 9, t);                          __syncthreads();
    }

    // measurement: fold the final CNOT ring into the probability gather.
    const int rp_t = ring_perm(t);
    float v[4] = {0.f, 0.f, 0.f, 0.f};
#pragma unroll
    for (int k = 0; k < 8; ++k) {
        const int src = rp_t ^ ((k & 4) ? ring_perm(1 << 10) : 0)
                             ^ ((k & 2) ? ring_perm(1 << 9)  : 0)
                             ^ ((k & 1) ? ring_perm(1 << 8)  : 0);
        const float2 a = S[swz(src)];
        const float p = a.x * a.x + a.y * a.y;
        v[0] += (k & 4) ? -p : p;          // qubit 0, bit pos 10
        v[1] += (k & 2) ? -p : p;          // qubit 1, bit pos 9
        v[2] += (k & 1) ? -p : p;          // qubit 2, bit pos 8
        v[3] += (t & 128) ? -p : p;        // qubit 3, bit pos 7
    }
#pragma unroll
    for (int q = 0; q < 4; ++q)
#pragma unroll
        for (int off = 32; off >= 1; off >>= 1)
            v[q] += __shfl_down(v[q], off, 64);
    if ((t & 63) == 0) {
#pragma unroll
        for (int q = 0; q < 4; ++q) red[t >> 6][q] = v[q];
    }
    __syncthreads();
    if (t < 4) {
        out[b * 4 + t] = red[0][t] + red[1][t] + red[2][t] + red[3][t];
    }
}

extern "C" void kernel_launch(void* const* d_in, const int* in_sizes, int n_in,
                              void* d_out, int out_size, void* d_ws, size_t ws_size,
                              hipStream_t stream) {
    const float* X  = (const float*)d_in[0];   // (16, 8)
    const float* W  = (const float*)d_in[1];   // (4, 11, 3)
    const float* Bi = (const float*)d_in[2];   // (4, 11, 3)
    float* out = (float*)d_out;                // (16, 4)
    qsim_kernel<<<16, 256, 0, stream>>>(X, W, Bi, out);
}

// Round 5
// 66.147 us; speedup vs baseline: 1.7518x; 1.0145x over previous
//
#include <hip/hip_runtime.h>

#define NQ 11
#define NL 4
#define NF 8
#define DIM 2048   // 2^11
#define NGATES (NL * NQ)  // 44

// Composed permutation of the CNOT ring (0,1)(1,2)...(9,10)(10,0).
// s_after_cnots[i] = s_before[ring_perm(i)]  (verified absmax==0 R1-R4).
// Linear over GF(2): ring_perm(a^b) = ring_perm(a)^ring_perm(b).
__host__ __device__ constexpr int ring_perm(int y) {
    int z = y ^ ((y & 1) << 10);
    for (int k = 10; k >= 1; --k)
        z ^= ((z >> (11 - k)) & 1) << (10 - k);
    return z;
}

// XOR bank swizzle: bijective, only touches bits 0..4 (chunk-preserving).
__device__ __forceinline__ int swz(int i) { return i ^ ((i >> 5) & 31); }

// Compiler-only reorder fence; HW DS in-order per wave handles the rest.
__device__ __forceinline__ void wave_sync() { __builtin_amdgcn_wave_barrier(); }

__device__ __forceinline__ float2 cmul(float2 a, float2 b) {
    return make_float2(a.x * b.x - a.y * b.y, a.x * b.y + a.y * b.x);
}

__device__ __forceinline__ void rot_pair(float2& a, float2& c,
                                         const float4 M0, const float4 M1) {
    float2 na, nc;
    na.x = M0.x * a.x - M0.y * a.y + M0.z * c.x - M0.w * c.y;
    na.y = M0.x * a.y + M0.y * a.x + M0.z * c.y + M0.w * c.x;
    nc.x = M1.x * a.x - M1.y * a.y + M1.z * c.x - M1.w * c.y;
    nc.y = M1.x * a.y + M1.y * a.x + M1.z * c.y + M1.w * c.x;
    a = na; c = nc;
}

// One LDS pass applying 3 single-qubit gates at bit positions P2>P1>P0.
// If PERM, reads are routed through ring_perm (folds the previous layer's
// CNOT ring into this pass's gather). Writes go to logical addresses.
template<int P2, int P1, int P0, bool PERM>
__device__ __forceinline__ void group3(const float2* __restrict__ src,
                                       float2* __restrict__ dst,
                                       const float (*gm)[8], int g, int base) {
    constexpr int E2 = 1 << P2, E1 = 1 << P1, E0 = 1 << P0;
    constexpr int K2 = PERM ? ring_perm(1 << P2) : (1 << P2);
    constexpr int K1 = PERM ? ring_perm(1 << P1) : (1 << P1);
    constexpr int K0 = PERM ? ring_perm(1 << P0) : (1 << P0);

    const float4* mA = (const float4*)gm[g];
    const float4* mB = (const float4*)gm[g + 1];
    const float4* mC = (const float4*)gm[g + 2];
    const float4 A0 = mA[0], A1 = mA[1];
    const float4 B0 = mB[0], B1 = mB[1];
    const float4 C0 = mC[0], C1 = mC[1];

    const int rb = PERM ? ring_perm(base) : base;
    float2 s[8];
#pragma unroll
    for (int k = 0; k < 8; ++k) {
        const int idx = rb ^ ((k & 4) ? K2 : 0) ^ ((k & 2) ? K1 : 0) ^ ((k & 1) ? K0 : 0);
        s[k] = src[swz(idx)];
    }
    rot_pair(s[0], s[4], A0, A1); rot_pair(s[1], s[5], A0, A1);
    rot_pair(s[2], s[6], A0, A1); rot_pair(s[3], s[7], A0, A1);
    rot_pair(s[0], s[2], B0, B1); rot_pair(s[1], s[3], B0, B1);
    rot_pair(s[4], s[6], B0, B1); rot_pair(s[5], s[7], B0, B1);
    rot_pair(s[0], s[1], C0, C1); rot_pair(s[2], s[3], C0, C1);
    rot_pair(s[4], s[5], C0, C1); rot_pair(s[6], s[7], C0, C1);
#pragma unroll
    for (int k = 0; k < 8; ++k) {
        const int a = base | ((k & 4) ? E2 : 0) | ((k & 2) ? E1 : 0) | ((k & 1) ? E0 : 0);
        dst[swz(a)] = s[k];
    }
}

// 2-qubit group at bit positions (1,0), WAVE-LOCAL mapping:
// thread t owns amps (t<<3)+{0..7} -> amp bits {10,9} == wave id.
__device__ __forceinline__ void group2q(float2* buf, const float (*gm)[8],
                                        int g, int t) {
    const float4* mB = (const float4*)gm[g];
    const float4* mC = (const float4*)gm[g + 1];
    const float4 B0 = mB[0], B1 = mB[1];
    const float4 C0 = mC[0], C1 = mC[1];
#pragma unroll
    for (int j = 0; j < 2; ++j) {
        const int base = (t << 3) | (j << 2);
        float2 s[4];
#pragma unroll
        for (int k = 0; k < 4; ++k) s[k] = buf[swz(base | k)];
        rot_pair(s[0], s[2], B0, B1); rot_pair(s[1], s[3], B0, B1);
        rot_pair(s[0], s[1], C0, C1); rot_pair(s[2], s[3], C0, C1);
#pragma unroll
        for (int k = 0; k < 4; ++k) buf[swz(base | k)] = s[k];
    }
}

__global__ __launch_bounds__(256)
void qsim_kernel(const float* __restrict__ X, const float* __restrict__ W,
                 const float* __restrict__ Bi, float* __restrict__ out)
{
    __shared__ float2 bufA[DIM];
    __shared__ float2 bufB[DIM];
    __shared__ __align__(16) float gm[NGATES][8];
    __shared__ float sc[3 * NGATES][2];   // per-angle {sin, cos}
    __shared__ float red[4][4];

    const int b = blockIdx.x;
    const int t = threadIdx.x;

    // --- stage 1: 132 sincosf in parallel (one per thread) ---
    if (t < 3 * NGATES) {
        const int g = t / 3, c = t - 3 * g;
        const int base = g * 3;
        const float x0 = X[b * NF + ((base + 0) & 7)];
        const float x1 = X[b * NF + ((base + 1) & 7)];
        const float x2 = X[b * NF + ((base + 2) & 7)];
        const float phi   = x0 * W[base + 0] + Bi[base + 0];
        const float theta = x1 * W[base + 1] + Bi[base + 1];
        const float omega = x2 * W[base + 2] + Bi[base + 2];
        const float arg = (c == 0) ? 0.5f * theta
                        : (c == 1) ? 0.5f * (phi + omega)
                                   : 0.5f * (phi - omega);
        float s_, c_; sincosf(arg, &s_, &c_);
        sc[t][0] = s_; sc[t][1] = c_;
    }
    __syncthreads();
    // --- stage 2: assemble 44 gate matrices ---
    if (t < NGATES) {
        const float sh  = sc[3 * t][0],     ch  = sc[3 * t][1];
        const float spo = sc[3 * t + 1][0], cpo = sc[3 * t + 1][1];
        const float spm = sc[3 * t + 2][0], cpm = sc[3 * t + 2][1];
        gm[t][0] =  cpo * ch;  gm[t][1] = -spo * ch;   // m00
        gm[t][2] = -cpm * sh;  gm[t][3] = -spm * sh;   // m01
        gm[t][4] =  cpm * sh;  gm[t][5] = -spm * sh;   // m10
        gm[t][6] =  cpo * ch;  gm[t][7] =  spo * ch;   // m11
    }
    __syncthreads();

    float2* S = bufA;
    float2* T = bufB;

    // --- layer 0 closed form: product state amp[x] = prod_q Mq[bit](0) ---
    {
        float2 c0[11], c1[11];
#pragma unroll
        for (int q = 0; q < 11; ++q) {
            c0[q] = make_float2(gm[q][0], gm[q][1]);   // m00
            c1[q] = make_float2(gm[q][4], gm[q][5]);   // m10
        }
        float2 P = ((t >> 0) & 1) ? c1[10] : c0[10];
#pragma unroll
        for (int bbit = 1; bbit < 8; ++bbit)
            P = cmul(P, ((t >> bbit) & 1) ? c1[10 - bbit] : c0[10 - bbit]);
        float2 t2[4];
        t2[0] = cmul(c0[1], c0[0]);
        t2[1] = cmul(c1[1], c0[0]);
        t2[2] = cmul(c0[1], c1[0]);
        t2[3] = cmul(c1[1], c1[0]);
#pragma unroll
        for (int k = 0; k < 8; ++k) {
            const float2 h = cmul((k & 1) ? c1[2] : c0[2], t2[k >> 1]);
            S[swz(t + 256 * k)] = cmul(P, h);
        }
    }
    __syncthreads();

    // layers 1..3. Only the perm-gather pass is cross-wave; the inner three
    // passes keep each wave inside its own 512-amp chunk (amp bits {10,9} ==
    // wave id; swz only touches bits 0..4), so they need no s_barrier —
    // per-wave in-order DS handles RAW through LDS.
    for (int l = 1; l < NL; ++l) {
        group3<10, 9, 8, true>(S, T, gm, l * NQ + 0, t); { float2* x = S; S = T; T = x; }
        __syncthreads();   // cross-wave pass done; chunks now private
        const int base765 = ((t >> 5) << 8) | (t & 31);
        const int base432 = ((t >> 2) << 5) | (t & 3);
        group3<7, 6, 5, false>(S, S, gm, l * NQ + 3, base765);  wave_sync();
        group3<4, 3, 2, false>(S, S, gm, l * NQ + 6, base432);  wave_sync();
        group2q(S, gm, l * NQ + 9, t);
        __syncthreads();   // publish chunks before next cross-wave gather
    }

    // measurement: fold the final CNOT ring into the probability gather.
    const int rp_t = ring_perm(t);
    float v[4] = {0.f, 0.f, 0.f, 0.f};
#pragma unroll
    for (int k = 0; k < 8; ++k) {
        const int src = rp_t ^ ((k & 4) ? ring_perm(1 << 10) : 0)
                             ^ ((k & 2) ? ring_perm(1 << 9)  : 0)
                             ^ ((k & 1) ? ring_perm(1 << 8)  : 0);
        const float2 a = S[swz(src)];
        const float p = a.x * a.x + a.y * a.y;
        v[0] += (k & 4) ? -p : p;          // qubit 0, bit pos 10
        v[1] += (k & 2) ? -p : p;          // qubit 1, bit pos 9
        v[2] += (k & 1) ? -p : p;          // qubit 2, bit pos 8
        v[3] += (t & 128) ? -p : p;        // qubit 3, bit pos 7
    }
#pragma unroll
    for (int q = 0; q < 4; ++q)
#pragma unroll
        for (int off = 32; off >= 1; off >>= 1)
            v[q] += __shfl_down(v[q], off, 64);
    if ((t & 63) == 0) {
#pragma unroll
        for (int q = 0; q < 4; ++q) red[t >> 6][q] = v[q];
    }
    __syncthreads();
    if (t < 4) {
        out[b * 4 + t] = red[0][t] + red[1][t] + red[2][t] + red[3][t];
    }
}

extern "C" void kernel_launch(void* const* d_in, const int* in_sizes, int n_in,
                              void* d_out, int out_size, void* d_ws, size_t ws_size,
                              hipStream_t stream) {
    const float* X  = (const float*)d_in[0];   // (16, 8)
    const float* W  = (const float*)d_in[1];   // (4, 11, 3)
    const float* Bi = (const float*)d_in[2];   // (4, 11, 3)
    float* out = (float*)d_out;                // (16, 4)
    qsim_kernel<<<16, 256, 0, stream>>>(X, W, Bi, out);
}